// Round 4
// baseline (325.978 us; speedup 1.0000x reference)
//
#include <hip/hip_runtime.h>

// burst:   (nd=32, c=3, 128, 128) fp32
// kernels: (nd=32, r=4, 5, 5, 128, 128) fp32
// out:     (nd=32, c=3, 256, 256) fp32 (pixel-shuffle s=2)
#define HH 128
#define WW 128
#define CC 3
#define RR 4
#define KK 5
#define ND 32
#define HW (HH * WW)

__global__ __launch_bounds__(256, 8) void adaptive_conv_ps(
    const float* __restrict__ burst,
    const float* __restrict__ kern,
    float* __restrict__ out)
{
    const int t  = blockIdx.x * 256 + threadIdx.x;
    const int w  = t & (WW - 1);
    const int h  = (t >> 7) & (HH - 1);
    const int nd = t >> 14;                 // wave-uniform

    // Wave-uniform base pointers (land in SGPRs) + per-thread 32-bit offsets.
    const float* b0 = burst + (size_t)nd * CC * HW;          // c = 0
    const float* b1 = b0 + HW;
    const float* b2 = b1 + HW;
    const float* kb0 = kern + (size_t)nd * RR * KK * KK * HW; // r = 0
    const float* kb1 = kb0 + KK * KK * HW;
    const float* kb2 = kb1 + KK * KK * HW;
    const float* kb3 = kb2 + KK * KK * HW;

    const int hw = h * WW + w;

    float acc[CC][RR];
#pragma unroll
    for (int c = 0; c < CC; ++c)
#pragma unroll
        for (int r = 0; r < RR; ++r)
            acc[c][r] = 0.0f;

#pragma unroll
    for (int i = 0; i < KK; ++i) {
        const int y  = h + i - 2;
        const int cy = min(max(y, 0), HH - 1);
        const bool vy = (unsigned)y < (unsigned)HH;
#pragma unroll
        for (int j = 0; j < KK; ++j) {
            const int x  = w + j - 2;
            const int cx = min(max(x, 0), WW - 1);
            const bool v = vy && ((unsigned)x < (unsigned)WW);
            const int boff = cy * WW + cx;       // always in-bounds

            // Burst taps: unconditional loads (L2-hot), select to zero at border.
            float p0 = b0[boff]; p0 = v ? p0 : 0.0f;
            float p1 = b1[boff]; p1 = v ? p1 : 0.0f;
            float p2 = b2[boff]; p2 = v ? p2 : 0.0f;

            // Kernel stream: 4 coalesced dword loads (tap-plane offset is a
            // compile-time constant in the unrolled loop).
            const int koff = (i * KK + j) * HW + hw;
            const float k0 = kb0[koff];
            const float k1 = kb1[koff];
            const float k2 = kb2[koff];
            const float k3 = kb3[koff];

            acc[0][0] += k0 * p0; acc[0][1] += k1 * p0;
            acc[0][2] += k2 * p0; acc[0][3] += k3 * p0;
            acc[1][0] += k0 * p1; acc[1][1] += k1 * p1;
            acc[1][2] += k2 * p1; acc[1][3] += k3 * p1;
            acc[2][0] += k0 * p2; acc[2][1] += k1 * p2;
            acc[2][2] += k2 * p2; acc[2][3] += k3 * p2;
        }
    }

    // Pixel-shuffle store: out[nd, c, 2h+si, 2w+sj] = acc[c][si*2+sj]
#pragma unroll
    for (int c = 0; c < CC; ++c) {
#pragma unroll
        for (int si = 0; si < 2; ++si) {
            float2 vv = make_float2(acc[c][si * 2 + 0], acc[c][si * 2 + 1]);
            float* o = out + (((size_t)(nd * CC + c) * (2 * HH) + (2 * h + si)) * (2 * WW))
                           + 2 * w;
            *(float2*)o = vv;
        }
    }
}

extern "C" void kernel_launch(void* const* d_in, const int* in_sizes, int n_in,
                              void* d_out, int out_size, void* d_ws, size_t ws_size,
                              hipStream_t stream) {
    const float* burst = (const float*)d_in[0];
    const float* kern  = (const float*)d_in[1];
    float* out = (float*)d_out;

    const int total = ND * HH * WW;          // 524288 threads, 1 px/thread
    adaptive_conv_ps<<<total / 256, 256, 0, stream>>>(burst, kern, out);
}